// Round 1
// 1546.271 us; speedup vs baseline: 2.3370x; 2.3370x over previous
//
#include <hip/hip_runtime.h>

#define NROWS 131072
#define KCB 512
#define DDIM 512
#define BM 32
#define NT 256
#define NSTEPS 48            // 3*512 / 32 kext per step
#define TAU_FLAG 0.02f       // flag row if (2nd_min - min) < this
#define TAU_CAND 0.01f       // exact-recheck candidates within min + this

typedef __attribute__((ext_vector_type(8))) __bf16 bf16x8;
typedef __attribute__((ext_vector_type(4))) float f32x4;
typedef __attribute__((ext_vector_type(8))) unsigned short u16x8;

__device__ __forceinline__ unsigned short f2bf(float f) {
    unsigned int u = __float_as_uint(f);
    return (unsigned short)((u + 0x7FFFu + ((u >> 16) & 1u)) >> 16);  // RNE
}
__device__ __forceinline__ float bf2f(unsigned short h) {
    return __uint_as_float(((unsigned int)h) << 16);
}

// ---------------------------------------------------------------------------
// pnorm[k] = sum_d P[k][d]^2  (identical to the verified fp32 kernel)
// ---------------------------------------------------------------------------
__global__ void pnorm_kernel(const float* __restrict__ P, float* __restrict__ pnorm) {
    int k = blockIdx.x * 64 + threadIdx.x;
    if (k >= KCB) return;
    const float4* p4 = (const float4*)P + (size_t)k * (DDIM / 4);
    float s = 0.f;
#pragma unroll 8
    for (int q = 0; q < DDIM / 4; ++q) {
        float4 v = p4[q];
        s += ((v.x * v.x + v.y * v.y) + (v.z * v.z + v.w * v.w));
    }
    pnorm[k] = s;
}

// ---------------------------------------------------------------------------
// Bext[kb][c][j], kb in [0,192): bf16 planes of P in MFMA-native layout.
//   kb <  64 : ph  (bf16 RNE of P),          k = kb*8 + j
//   kb < 128 : pl  (bf16 of residual),       k = (kb-64)*8 + j
//   kb < 192 : ph  again (for the zl pass),  k = (kb-128)*8 + j
// Layout: element offset = (kb*512 + c)*8 + j  -> 16B per (kb,c), linear
// so the main kernel stages it with plain global_load_lds.
// ---------------------------------------------------------------------------
__global__ void bext_kernel(const float* __restrict__ P, unsigned short* __restrict__ Bext) {
    int kb = blockIdx.x;           // 0..191
    int c = threadIdx.x;           // 0..511
    int k0 = (kb & 63) * 8;
    const float* pr = P + (size_t)c * DDIM + k0;
    bool lo = (kb >= 64 && kb < 128);
    u16x8 o;
#pragma unroll
    for (int j = 0; j < 8; ++j) {
        float v = pr[j];
        unsigned short h = f2bf(v);
        o[j] = lo ? f2bf(v - bf2f(h)) : h;
    }
    *(u16x8*)(Bext + ((size_t)kb * KCB + c) * 8) = o;
}

// ---------------------------------------------------------------------------
// Stage one K-step (4 kb-slices = 32 KB) of Bext into LDS, linear, 16B/lane.
// ---------------------------------------------------------------------------
__device__ __forceinline__ void stageB(const unsigned short* __restrict__ Bext,
                                       int s, unsigned short* dst, int tid) {
#pragma unroll
    for (int t = 0; t < 8; ++t) {
        int i = t * NT + tid;      // 2048 chunks of 16B per step
        __builtin_amdgcn_global_load_lds(
            (__attribute__((address_space(1))) void*)(Bext + (size_t)s * 16384 + i * 8),
            (__attribute__((address_space(3))) void*)(dst + i * 8),
            16, 0, 0);
    }
}

// ---------------------------------------------------------------------------
// Fused bf16x2 MFMA GEMM (z @ P^T) + argmin (+ exact fp32 recheck of
// near-ties) + gather + blend.
// Block: 256 threads = 4 waves; BM=32 rows; wave w owns cols [128w,128w+128).
// A (zh/zl) persisted in LDS [kb][row][8]; B double-buffered 32KB steps.
// ---------------------------------------------------------------------------
__global__ __launch_bounds__(NT, 1) void vq_kernel(
    const float* __restrict__ z, const float* __restrict__ P,
    const float* __restrict__ pnorm, const unsigned short* __restrict__ Bext,
    float* __restrict__ out)
{
    __shared__ unsigned short zh[64 * BM * 8];      // 32 KB [kb][row][8]
    __shared__ unsigned short zl[64 * BM * 8];      // 32 KB
    __shared__ unsigned short bb[2][4 * KCB * 8];   // 64 KB [kbl][col][8] x2
    __shared__ float pn_s[KCB];
    __shared__ float znp[BM][8];
    __shared__ float znorm_s[BM];
    __shared__ float bvs[BM];
    __shared__ int sidx[BM];
    __shared__ int flagf[BM];
    __shared__ int flist[BM];
    __shared__ int nflag, ccnt;

    const int tid = threadIdx.x;
    const int wv = tid >> 6, ln = tid & 63;
    const int g = ln >> 4, lr = ln & 15;   // lane -> (k-subblock, row/col-in-tile)
    const int wcol0 = wv * 128;
    const int n0 = blockIdx.x * BM;
    const float4* Z4 = (const float4*)z;
    const float4* P4 = (const float4*)P;

    // ---- stage pnorm ----
    for (int i = tid; i < KCB; i += NT) pn_s[i] = pnorm[i];

    // ---- znorm partials: byte-identical arithmetic to the passing kernel ----
    {
        int row = tid >> 3, seg = tid & 7;
        const float4* zp = Z4 + (size_t)(n0 + row) * (DDIM / 4) + seg * 16;
        float s = 0.f;
#pragma unroll
        for (int u = 0; u < 16; ++u) {
            float4 v = zp[u];
            s += ((v.x * v.x + v.y * v.y) + (v.z * v.z + v.w * v.w));
        }
        znp[row][seg] = s;
    }

    // ---- convert z slab -> zh/zl (bf16 hi/lo) into LDS [kb][row][8] ----
    // row-major-in-lanes mapping => conflict-free ds_write_b128; global reads
    // are L2 hits (slab just read by the znorm pass).
    {
        int row = tid & 31, kbg = tid >> 5;
#pragma unroll
        for (int it = 0; it < 8; ++it) {
            int kb = kbg + 8 * it;
            float4 a = Z4[(size_t)(n0 + row) * (DDIM / 4) + kb * 2];
            float4 b = Z4[(size_t)(n0 + row) * (DDIM / 4) + kb * 2 + 1];
            float f[8] = {a.x, a.y, a.z, a.w, b.x, b.y, b.z, b.w};
            u16x8 vh, vl;
#pragma unroll
            for (int j = 0; j < 8; ++j) {
                unsigned short h = f2bf(f[j]);
                vh[j] = h;
                vl[j] = f2bf(f[j] - bf2f(h));
            }
            *(u16x8*)&zh[(kb * BM + row) * 8] = vh;
            *(u16x8*)&zl[(kb * BM + row) * 8] = vl;
        }
    }

    // ---- prefetch B step 0 ----
    stageB(Bext, 0, &bb[0][0], tid);

    __syncthreads();

    if (tid < BM) {
        float s = 0.f;
#pragma unroll
        for (int j = 0; j < 8; ++j) s += znp[tid][j];
        znorm_s[tid] = s;   // consumed only in the recheck phase (post-barriers)
    }

    // ---- K-loop: kext = [zh.ph | zh.pl | zl.ph], 48 steps of 32 ----
    f32x4 acc[2][8];
#pragma unroll
    for (int r = 0; r < 2; ++r)
#pragma unroll
        for (int c = 0; c < 8; ++c) acc[r][c] = (f32x4)0.f;

    for (int s = 0; s < NSTEPS; ++s) {
        const int cur = s & 1;
        if (s + 1 < NSTEPS) stageB(Bext, s + 1, &bb[cur ^ 1][0], tid);  // stage-before-compute

        const unsigned short* ap = (s < 32) ? zh : zl;
        const int kbA = (4 * s) & 63;
        // A-frags: lane -> row (lr | lr+16), k = (kbA+g)*8 + j  (contiguous 16B)
        bf16x8 aF0 = *(const bf16x8*)&ap[((kbA + g) * BM + lr) * 8];
        bf16x8 aF1 = *(const bf16x8*)&ap[((kbA + g) * BM + 16 + lr) * 8];
#pragma unroll
        for (int ct = 0; ct < 8; ++ct) {
            bf16x8 bF = *(const bf16x8*)&bb[cur][(g * KCB + wcol0 + ct * 16 + lr) * 8];
            acc[0][ct] = __builtin_amdgcn_mfma_f32_16x16x32_bf16(aF0, bF, acc[0][ct], 0, 0, 0);
            acc[1][ct] = __builtin_amdgcn_mfma_f32_16x16x32_bf16(aF1, bF, acc[1][ct], 0, 0, 0);
        }
        __syncthreads();   // staging of s+1 drained; all waves done reading cur
    }

    // ---- epilogue scratch overlays the (dead) B buffers ----
    float* redv = (float*)&bb[0][0];        // 8 KB  [row][64]
    float* red2 = redv + BM * 64;           // 8 KB
    int* redi = (int*)(red2 + BM * 64);     // 8 KB
    int* clist = (int*)(redi + BM * 64);    // 2 KB (512 entries)
    float* cval = (float*)(clist + 512);    // 2 KB

    if (tid == 0) { nflag = 0; ccnt = 0; }

    // per-thread (min, idx, 2nd-min) over its 8 rows x 8 cols
    // D-frag mapping (m89): col = wcol0 + ct*16 + lr, row = rt*16 + g*4 + rg
#pragma unroll
    for (int rt = 0; rt < 2; ++rt) {
#pragma unroll
        for (int rg = 0; rg < 4; ++rg) {
            int row = rt * 16 + g * 4 + rg;
            float m1 = 1e30f, m2 = 1e30f;
            int i1 = 0;
#pragma unroll
            for (int ct = 0; ct < 8; ++ct) {
                int k = wcol0 + ct * 16 + lr;
                float v = pn_s[k] - 2.0f * acc[rt][ct][rg];  // znorm omitted (row-constant)
                if (v < m1) { m2 = m1; m1 = v; i1 = k; }
                else m2 = fminf(m2, v);
            }
            int slot = wv * 16 + lr;
            redv[row * 64 + slot] = m1;
            red2[row * 64 + slot] = m2;
            redi[row * 64 + slot] = i1;
        }
    }
    __syncthreads();

    // cross-thread reduce: lexicographic (val, idx) + global second-min
    if (tid < BM) {
        float bv = 1e30f, sv = 1e30f;
        int bi = 0x7FFFFFFF;
        for (int t = 0; t < 64; ++t) {
            float v1 = redv[tid * 64 + t];
            float v2 = red2[tid * 64 + t];
            int i1 = redi[tid * 64 + t];
            if (v1 < bv || (v1 == bv && i1 < bi)) {
                sv = fminf(sv, bv);
                bv = v1; bi = i1;
                sv = fminf(sv, v2);
            } else {
                sv = fminf(sv, v1);
            }
        }
        sidx[tid] = bi;
        bvs[tid] = bv;
        int f = (sv - bv) < TAU_FLAG;
        flagf[tid] = f;
        if (f) { int p = atomicAdd(&nflag, 1); flist[p] = tid; }
    }
    __syncthreads();

    // collect exact-recheck candidates for flagged rows (approx within cutoff)
    if (nflag > 0) {
#pragma unroll
        for (int rt = 0; rt < 2; ++rt) {
#pragma unroll
            for (int rg = 0; rg < 4; ++rg) {
                int row = rt * 16 + g * 4 + rg;
                if (flagf[row]) {
                    float cut = bvs[row] + TAU_CAND;
#pragma unroll
                    for (int ct = 0; ct < 8; ++ct) {
                        int k = wcol0 + ct * 16 + lr;
                        float v = pn_s[k] - 2.0f * acc[rt][ct][rg];
                        if (v <= cut) {
                            int p = atomicAdd(&ccnt, 1);
                            if (p < 512) clist[p] = (row << 16) | k;
                        }
                    }
                }
            }
        }
    }
    __syncthreads();

    // exact fp32 eval of candidates: ascending-d FMA chain + (zn+pn)-2*dot,
    // byte-identical arithmetic to the previously-passing fp32 kernel.
    int nc = min(ccnt, 512);
    for (int i = tid; i < nc; i += NT) {
        int e = clist[i];
        int row = e >> 16, k = e & 0xFFFF;
        const float4* zp = Z4 + (size_t)(n0 + row) * (DDIM / 4);
        const float4* pp = P4 + (size_t)k * (DDIM / 4);
        float s = 0.f;
        for (int q = 0; q < DDIM / 4; ++q) {
            float4 a = zp[q], b = pp[q];
            s += a.x * b.x; s += a.y * b.y; s += a.z * b.z; s += a.w * b.w;
        }
        float t1 = znorm_s[row] + pn_s[k];
        cval[i] = t1 - 2.0f * s;
    }
    __syncthreads();

    if (tid < nflag) {
        int row = flist[tid];
        float bv = 1e30f;
        int bi = 0x7FFFFFFF;
        for (int i = 0; i < nc; ++i) {
            int e = clist[i];
            if ((e >> 16) == row) {
                float v = cval[i];
                int k = e & 0xFFFF;
                if (v < bv || (v == bv && k < bi)) { bv = v; bi = k; }
            }
        }
        sidx[row] = bi;
    }
    __syncthreads();

    if (tid < BM) out[(size_t)2 * NROWS * DDIM + n0 + tid] = (float)sidx[tid];

    // gather z_tilde = P[idx] (exact fp32), blend z_hat = 0.7 z + 0.3 z_tilde
    float4* outh = (float4*)out;
    float4* outt = (float4*)out + (size_t)NROWS * (DDIM / 4);
    for (int i = tid; i < BM * (DDIM / 4); i += NT) {
        int row = i >> 7, q = i & 127;
        int kk = sidx[row];
        float4 pv = P4[(size_t)kk * (DDIM / 4) + q];
        float4 zv = Z4[(size_t)(n0 + row) * (DDIM / 4) + q];
        float4 zb;
        zb.x = 0.7f * zv.x + 0.3f * pv.x;
        zb.y = 0.7f * zv.y + 0.3f * pv.y;
        zb.z = 0.7f * zv.z + 0.3f * pv.z;
        zb.w = 0.7f * zv.w + 0.3f * pv.w;
        size_t o = (size_t)(n0 + row) * (DDIM / 4) + q;
        outh[o] = zb;
        outt[o] = pv;
    }
}

extern "C" void kernel_launch(void* const* d_in, const int* in_sizes, int n_in,
                              void* d_out, int out_size, void* d_ws, size_t ws_size,
                              hipStream_t stream) {
    const float* z = (const float*)d_in[0];
    const float* P = (const float*)d_in[1];
    float* pnorm = (float*)d_ws;                                   // 2 KB
    unsigned short* Bext = (unsigned short*)((char*)d_ws + 2048);  // 1.5 MB

    pnorm_kernel<<<dim3(KCB / 64), dim3(64), 0, stream>>>(P, pnorm);
    bext_kernel<<<dim3(192), dim3(512), 0, stream>>>(P, Bext);
    vq_kernel<<<dim3(NROWS / BM), dim3(NT), 0, stream>>>(z, P, pnorm, Bext, (float*)d_out);
}